// Round 10
// baseline (431.780 us; speedup 1.0000x reference)
//
#include <hip/hip_runtime.h>
#include <hip/hip_cooperative_groups.h>
#include <hip/hip_bf16.h>

#define NN 2048
#define DD 128
#define HH 8
#define HDIM 16
#define LL 8
#define GG 16
#define BNEPS 1e-5f

namespace cg = cooperative_groups;

typedef unsigned int u32;
typedef unsigned long long u64;
typedef __attribute__((ext_vector_type(8))) short bf16x8;
typedef __attribute__((ext_vector_type(8))) unsigned short us8;
typedef __attribute__((ext_vector_type(4))) float f32x4;

__device__ __forceinline__ unsigned short f2bf(float f) {
    union { float f; u32 u; } v; v.f = f;
    u32 u = v.u;
    u32 r = (u + 0x7fffu + ((u >> 16) & 1u)) >> 16;
    return (unsigned short)r;
}

// ---------------- workspace zeroing (graph-capture-safe) ----------------
__global__ __launch_bounds__(256) void zero_k(uint4* __restrict__ p) {
    p[blockIdx.x * 256 + threadIdx.x] = make_uint4(0u, 0u, 0u, 0u);
}

// ---------------- adjacency build ----------------
__global__ __launch_bounds__(256) void scatter_k(const int* __restrict__ ei, u32* __restrict__ A, int E) {
    int e = blockIdx.x * 256 + threadIdx.x;
    if (e < E) {
        int s = ei[e];
        int d = ei[E + e];
        atomicAdd(&A[s * NN + d], 1u);
    }
}

__global__ __launch_bounds__(256) void count_k(const u32* __restrict__ A, u32* __restrict__ deg) {
    int r = blockIdx.x, t = threadIdx.x;
    __shared__ u32 sb[256];
    u32 c = 0;
    for (int j = t; j < NN; j += 256) c += (A[r * NN + j] != 0u) ? 1u : 0u;
    sb[t] = c; __syncthreads();
    for (int off = 128; off; off >>= 1) { if (t < off) sb[t] += sb[t + off]; __syncthreads(); }
    if (t == 0) deg[r] = sb[0];
}

__global__ __launch_bounds__(256) void scan_k(const u32* __restrict__ deg, u32* __restrict__ rowptr) {
    __shared__ u32 part[256];
    int t = threadIdx.x;
    u32 loc[8]; u32 s = 0;
#pragma unroll
    for (int i = 0; i < 8; i++) { loc[i] = deg[t * 8 + i]; s += loc[i]; }
    part[t] = s; __syncthreads();
    for (int off = 1; off < 256; off <<= 1) {
        u32 vprev = (t >= off) ? part[t - off] : 0u;
        __syncthreads();
        part[t] += vprev;
        __syncthreads();
    }
    u32 run = (t == 0) ? 0u : part[t - 1];
    if (t == 0) rowptr[0] = 0u;
#pragma unroll
    for (int i = 0; i < 8; i++) { run += loc[i]; rowptr[t * 8 + i + 1] = run; }
}

__global__ __launch_bounds__(256) void emit_k(const u32* __restrict__ A, const u32* __restrict__ rowptr,
                                              u32* __restrict__ colidx, u32* __restrict__ cntv) {
    int r = blockIdx.x, tid = threadIdx.x;
    int lane = tid & 63, wid = tid >> 6;
    __shared__ u32 wsum[4];
    u32 base = rowptr[r];
    u32 cb = 0;
    for (int c0 = 0; c0 < NN; c0 += 256) {
        int c = c0 + tid;
        u32 a = A[r * NN + c];
        bool p = (a != 0u);
        u64 bal = __ballot(p);
        u32 rankw = (u32)__popcll(bal & ((1ull << lane) - 1ull));
        if (lane == 0) wsum[wid] = (u32)__popcll(bal);
        __syncthreads();
        u32 woff = 0;
#pragma unroll
        for (int w2 = 0; w2 < 4; w2++) if (w2 < wid) woff += wsum[w2];
        u32 tot = wsum[0] + wsum[1] + wsum[2] + wsum[3];
        if (p) { u32 pos = base + cb + woff + rankw; colidx[pos] = (u32)c; cntv[pos] = a; }
        cb += tot;
        __syncthreads();
    }
}

// ---------------- weight fragment conversion ----------------
__global__ __launch_bounds__(256) void wconv_k(const float* __restrict__ Wq, const float* __restrict__ Wk,
                                               const float* __restrict__ Wv, const float* __restrict__ Wo,
                                               const float* __restrict__ W1, const float* __restrict__ W2,
                                               us8* __restrict__ Wf) {
    int tid = blockIdx.x * 256 + threadIdx.x;   // 0..131071
    int layer = tid >> 14;
    int r = tid & 16383;
    const float* src;
    int s, NT, ld;
    if (r < 8192) {
        int reg = r >> 11;
        s = r & 2047;
        NT = 8; ld = 128;
        const float* bases[4] = {Wq, Wk, Wv, Wo};
        src = bases[reg] + layer * 16384;
    } else if (r < 12288) {
        s = r - 8192;
        NT = 16; ld = 256;
        src = W1 + layer * 32768;
    } else {
        s = r - 12288;
        NT = 8; ld = 128;
        src = W2 + layer * 32768;
    }
    int lane = s & 63;
    int t = s >> 6;
    int nt = t % NT;
    int kt = t / NT;
    int col = nt * 16 + (lane & 15);
    int k0 = kt * 32 + (lane >> 4) * 8;
    us8 o;
#pragma unroll
    for (int j = 0; j < 8; j++) o[j] = f2bf(src[(k0 + j) * ld + col]);
    Wf[tid] = o;
}

// ---------------- input projection ----------------
__global__ __launch_bounds__(256) void h0_k(const float* __restrict__ X, const float* __restrict__ pe,
                                            const float* __restrict__ pW, const float* __restrict__ pb,
                                            const float* __restrict__ peW, const float* __restrict__ peb,
                                            float* __restrict__ h) {
    int idx = blockIdx.x * 256 + threadIdx.x;
    int r = idx >> 7, d = idx & 127;
    float acc = pb[d] + peb[d];
    acc += X[r * 4 + 0] * pW[0 * DD + d];
    acc += X[r * 4 + 1] * pW[1 * DD + d];
    acc += X[r * 4 + 2] * pW[2 * DD + d];
    acc += X[r * 4 + 3] * pW[3 * DD + d];
    acc += pe[r * 2 + 0] * peW[0 * DD + d];
    acc += pe[r * 2 + 1] * peW[1 * DD + d];
    h[idx] = acc;
}

// ---------------- stats finalize (256-thread parallel) ----------------
__device__ __forceinline__ void finalize_stats2(const float* __restrict__ ps, const float* __restrict__ pss,
                                                const float* __restrict__ gamma, const float* __restrict__ beta,
                                                float* aS, float* cS, float* sred, int tidx) {
    if (ps) {
        int d = tidx & 127, half = tidx >> 7;
        float s = 0.f, s2 = 0.f;
        const float* p0 = ps + half * 64 * 128 + d;
        const float* p1 = pss + half * 64 * 128 + d;
#pragma unroll 8
        for (int i = 0; i < 64; i++) { s += p0[i * 128]; s2 += p1[i * 128]; }
        sred[tidx] = s;
        sred[256 + tidx] = s2;
        __syncthreads();
        if (tidx < 128) {
            float st = sred[tidx] + sred[tidx + 128];
            float s2t = sred[256 + tidx] + sred[256 + tidx + 128];
            float mean = st * (1.0f / NN);
            float var = s2t * (1.0f / NN) - mean * mean;
            float rstd = rsqrtf(var + BNEPS);
            float a = gamma[tidx] * rstd;
            aS[tidx] = a;
            cS[tidx] = beta[tidx] - mean * a;
        }
    } else if (tidx < 128) {
        aS[tidx] = 1.f;
        cS[tidx] = 0.f;
    }
}

// ================= phase device functions =================
__device__ void qkv_phase(const float* __restrict__ t,
                          const float* __restrict__ ps, const float* __restrict__ pss,
                          const float* __restrict__ gamma, const float* __restrict__ beta,
                          const bf16x8* __restrict__ Wfl,
                          const float* __restrict__ bq, const float* __restrict__ bk,
                          const float* __restrict__ bv,
                          float* __restrict__ q, float* __restrict__ k, float* __restrict__ v,
                          float* __restrict__ psv, int strip, int tidx) {
    __shared__ float aS[128], cS[128], sred[512];
    finalize_stats2(ps, pss, gamma, beta, aS, cS, sred, tidx);
    __syncthreads();
    int m0 = strip * 16;
    int lane = tidx & 63, wv = tidx >> 6;
    int arow = m0 + (lane & 15);
    int k0b = (lane >> 4) * 8;
    bf16x8 af[4];
#pragma unroll
    for (int kt = 0; kt < 4; kt++) {
        int k0 = kt * 32 + k0b;
        const float* tp = t + arow * DD + k0;
        float4 v0 = *(const float4*)(tp);
        float4 v1 = *(const float4*)(tp + 4);
        float vals[8] = {v0.x, v0.y, v0.z, v0.w, v1.x, v1.y, v1.z, v1.w};
        bf16x8 f;
#pragma unroll
        for (int j = 0; j < 8; j++) f[j] = (short)f2bf(vals[j] * aS[k0 + j] + cS[k0 + j]);
        af[kt] = f;
    }
#pragma unroll
    for (int ti = 0; ti < 6; ti++) {
        int tile = wv * 6 + ti;
        int mat = tile >> 3, nt = tile & 7;
        const bf16x8* wb = Wfl + mat * 2048;
        f32x4 acc = {0.f, 0.f, 0.f, 0.f};
#pragma unroll
        for (int kt = 0; kt < 4; kt++)
            acc = __builtin_amdgcn_mfma_f32_16x16x32_bf16(af[kt], wb[(kt * 8 + nt) * 64 + lane], acc, 0, 0, 0);
        const float* bias = (mat == 0) ? bq : ((mat == 1) ? bk : bv);
        float* outp = (mat == 0) ? q : ((mat == 1) ? k : v);
        float scale = (mat == 0) ? 0.25f : 1.0f;
        int col = nt * 16 + (lane & 15);
        int r0 = m0 + (lane >> 4) * 4;
        float bb = bias[col];
        float vals[4];
#pragma unroll
        for (int j = 0; j < 4; j++) {
            vals[j] = (acc[j] + bb) * scale;
            outp[(r0 + j) * DD + col] = vals[j];
        }
        if (mat == 2) {
            float cs = vals[0] + vals[1] + vals[2] + vals[3];
            cs += __shfl_xor(cs, 16);
            cs += __shfl_xor(cs, 32);
            if (lane < 16) psv[strip * 128 + col] = cs;
        }
    }
}

__device__ void attn_phase(const float* __restrict__ q, const float* __restrict__ kb,
                           const float* __restrict__ vb, const u32* __restrict__ rowptr,
                           const u32* __restrict__ colidx, const u32* __restrict__ cntv,
                           const float* __restrict__ psv, unsigned short* __restrict__ obb,
                           int bid, int tid) {
    int hh = bid >> 7;
    __shared__ float vred[16][17];
    __shared__ float vsS[16];
    {
        int d = tid & 15, part = tid >> 4;
        int strip = hh * 16 + part;
        float s = 0.f;
#pragma unroll
        for (int i = 0; i < 8; i++) s += psv[strip * 128 + i * 16 + d];
        vred[d][part] = s;
    }
    __syncthreads();
    if (tid < 16) {
        float s = 0.f;
#pragma unroll
        for (int i = 0; i < 16; i++) s += vred[tid][i];
        vsS[tid] = s;
    }
    __syncthreads();

    int lane = tid & 15;
    int gidx = bid * 16 + (tid >> 4);
    int nn = gidx & (NN - 1);
    const float* qr = q + hh * (NN * HDIM) + nn * HDIM;
    float qv[16];
    *(float4*)&qv[0]  = *(const float4*)(qr + 0);
    *(float4*)&qv[4]  = *(const float4*)(qr + 4);
    *(float4*)&qv[8]  = *(const float4*)(qr + 8);
    *(float4*)&qv[12] = *(const float4*)(qr + 12);
    int rs = (int)rowptr[nn], re = (int)rowptr[nn + 1];
    int deg = re - rs;

    float s[8];
    int mc[8];
    float lm = -1e30f;
#pragma unroll
    for (int ch = 0; ch < 8; ch++) {
        s[ch] = -1e30f; mc[ch] = 0;
        if (ch * 16 < deg) {
            int e = rs + ch * 16 + lane;
            if (e < re) {
                mc[ch] = (int)colidx[e];
                float c = (float)cntv[e];
                const float* kr = kb + hh * (NN * HDIM) + mc[ch] * HDIM;
                float kv[16];
                *(float4*)&kv[0]  = *(const float4*)(kr + 0);
                *(float4*)&kv[4]  = *(const float4*)(kr + 4);
                *(float4*)&kv[8]  = *(const float4*)(kr + 8);
                *(float4*)&kv[12] = *(const float4*)(kr + 12);
                float d = 0.f;
#pragma unroll
                for (int i = 0; i < 16; i++) d += qv[i] * kv[i];
                s[ch] = c * d;
            }
            lm = fmaxf(lm, s[ch]);
        }
    }
    for (int base = rs + 128; base < re; base += 16) {
        int e = base + lane;
        if (e < re) {
            int m2 = (int)colidx[e];
            float c = (float)cntv[e];
            const float* kr = kb + hh * (NN * HDIM) + m2 * HDIM;
            float d = 0.f;
#pragma unroll
            for (int i = 0; i < 16; i++) d += qv[i] * kr[i];
            lm = fmaxf(lm, c * d);
        }
    }
#pragma unroll
    for (int off = 1; off < 16; off <<= 1) lm = fmaxf(lm, __shfl_xor(lm, off));
    float rowmax = fmaxf(lm, 0.f);
    float em = __expf(-rowmax);

    float z = 0.f;
    float acc[16];
#pragma unroll
    for (int i = 0; i < 16; i++) acc[i] = 0.f;
#pragma unroll
    for (int ch = 0; ch < 8; ch++) {
        if (ch * 16 < deg) {
            int e = rs + ch * 16 + lane;
            if (e < re) {
                float w = __expf(s[ch] - rowmax);
                z += w;
                float coef = w - em;
                const float* vr = vb + hh * (NN * HDIM) + mc[ch] * HDIM;
                float vv[16];
                *(float4*)&vv[0]  = *(const float4*)(vr + 0);
                *(float4*)&vv[4]  = *(const float4*)(vr + 4);
                *(float4*)&vv[8]  = *(const float4*)(vr + 8);
                *(float4*)&vv[12] = *(const float4*)(vr + 12);
#pragma unroll
                for (int i = 0; i < 16; i++) acc[i] += coef * vv[i];
            }
        }
    }
    for (int base = rs + 128; base < re; base += 16) {
        int e = base + lane;
        if (e < re) {
            int m2 = (int)colidx[e];
            float c = (float)cntv[e];
            const float* kr = kb + hh * (NN * HDIM) + m2 * HDIM;
            float d = 0.f;
#pragma unroll
            for (int i = 0; i < 16; i++) d += qv[i] * kr[i];
            float w = __expf(c * d - rowmax);
            z += w;
            float coef = w - em;
            const float* vr = vb + hh * (NN * HDIM) + m2 * HDIM;
#pragma unroll
            for (int i = 0; i < 16; i++) acc[i] += coef * vr[i];
        }
    }
#pragma unroll
    for (int off = 1; off < 16; off <<= 1) {
        z += __shfl_xor(z, off);
#pragma unroll
        for (int i = 0; i < 16; i++) acc[i] += __shfl_xor(acc[i], off);
    }
    if (lane == 0) {
        float Z = z + (float)(NN - deg) * em;
        float inv = 1.f / Z;
        unsigned short* orow = obb + hh * (NN * HDIM) + nn * HDIM;
        us8 lo, hi;
#pragma unroll
        for (int i = 0; i < 8; i++) {
            lo[i] = f2bf((acc[i] + em * vsS[i]) * inv);
            hi[i] = f2bf((acc[i + 8] + em * vsS[i + 8]) * inv);
        }
        *(us8*)(orow + 0) = lo;
        *(us8*)(orow + 8) = hi;
    }
}

__device__ void gemmO_phase(const unsigned short* __restrict__ obb,
                            const bf16x8* __restrict__ Wfo,
                            const float* __restrict__ bo,
                            const float* __restrict__ tprev,
                            const float* __restrict__ ps, const float* __restrict__ pss,
                            const float* __restrict__ gamma, const float* __restrict__ beta,
                            float* __restrict__ t1,
                            float* __restrict__ ps1, float* __restrict__ pss1, int strip, int tidx) {
    __shared__ float aS[128], cS[128], sred[512];
    finalize_stats2(ps, pss, gamma, beta, aS, cS, sred, tidx);
    __syncthreads();
    int m0 = strip * 16;
    int lane = tidx & 63, wv = tidx >> 6;
    int arow = m0 + (lane & 15);
    int k0b = (lane >> 4) * 8;
    bf16x8 af[4];
#pragma unroll
    for (int kt = 0; kt < 4; kt++)
        af[kt] = *(const bf16x8*)(obb + arow * DD + kt * 32 + k0b);
#pragma unroll
    for (int ti = 0; ti < 2; ti++) {
        int nt = wv * 2 + ti;
        f32x4 acc = {0.f, 0.f, 0.f, 0.f};
#pragma unroll
        for (int kt = 0; kt < 4; kt++)
            acc = __builtin_amdgcn_mfma_f32_16x16x32_bf16(af[kt], Wfo[(kt * 8 + nt) * 64 + lane], acc, 0, 0, 0);
        int col = nt * 16 + (lane & 15);
        int r0 = m0 + (lane >> 4) * 4;
        float bb = bo[col];
        float a = aS[col], c = cS[col];
        float sum = 0.f, sumsq = 0.f;
#pragma unroll
        for (int j = 0; j < 4; j++) {
            float res = tprev[(r0 + j) * DD + col] * a + c;
            float v0 = acc[j] + bb + res;
            t1[(r0 + j) * DD + col] = v0;
            sum += v0; sumsq += v0 * v0;
        }
        sum += __shfl_xor(sum, 16);  sum += __shfl_xor(sum, 32);
        sumsq += __shfl_xor(sumsq, 16); sumsq += __shfl_xor(sumsq, 32);
        if (lane < 16) { ps1[strip * 128 + col] = sum; pss1[strip * 128 + col] = sumsq; }
    }
}

__device__ void mlp_phase(const float* __restrict__ t1,
                          const float* __restrict__ ps1, const float* __restrict__ pss1,
                          const float* __restrict__ g1, const float* __restrict__ be1,
                          const bf16x8* __restrict__ Wf1, const float* __restrict__ b1,
                          const bf16x8* __restrict__ Wf2, const float* __restrict__ b2,
                          float* __restrict__ t2,
                          float* __restrict__ ps2, float* __restrict__ pss2, int strip, int tidx) {
    __shared__ float aS[128], cS[128], sred[512];
    __shared__ unsigned short midL[16][264];
    finalize_stats2(ps1, pss1, g1, be1, aS, cS, sred, tidx);
    __syncthreads();
    int m0 = strip * 16;
    int lane = tidx & 63, wv = tidx >> 6;
    int lrow = lane & 15;
    int arow = m0 + lrow;
    int k0b = (lane >> 4) * 8;
    bf16x8 af[4];
#pragma unroll
    for (int kt = 0; kt < 4; kt++) {
        int k0 = kt * 32 + k0b;
        const float* tp = t1 + arow * DD + k0;
        float4 v0 = *(const float4*)(tp);
        float4 v1 = *(const float4*)(tp + 4);
        float vals[8] = {v0.x, v0.y, v0.z, v0.w, v1.x, v1.y, v1.z, v1.w};
        bf16x8 f;
#pragma unroll
        for (int j = 0; j < 8; j++) f[j] = (short)f2bf(vals[j] * aS[k0 + j] + cS[k0 + j]);
        af[kt] = f;
    }
#pragma unroll
    for (int ti = 0; ti < 4; ti++) {
        int nt = wv * 4 + ti;
        f32x4 acc = {0.f, 0.f, 0.f, 0.f};
#pragma unroll
        for (int kt = 0; kt < 4; kt++)
            acc = __builtin_amdgcn_mfma_f32_16x16x32_bf16(af[kt], Wf1[(kt * 16 + nt) * 64 + lane], acc, 0, 0, 0);
        int col = nt * 16 + (lane & 15);
        int r0l = (lane >> 4) * 4;
        float bb = b1[col];
#pragma unroll
        for (int j = 0; j < 4; j++)
            midL[r0l + j][col] = f2bf(fmaxf(acc[j] + bb, 0.f));
    }
    __syncthreads();
    bf16x8 af2[8];
#pragma unroll
    for (int kt = 0; kt < 8; kt++)
        af2[kt] = *(const bf16x8*)(&midL[lrow][kt * 32 + k0b]);
#pragma unroll
    for (int ti = 0; ti < 2; ti++) {
        int nt = wv * 2 + ti;
        f32x4 acc = {0.f, 0.f, 0.f, 0.f};
#pragma unroll
        for (int kt = 0; kt < 8; kt++)
            acc = __builtin_amdgcn_mfma_f32_16x16x32_bf16(af2[kt], Wf2[(kt * 8 + nt) * 64 + lane], acc, 0, 0, 0);
        int col = nt * 16 + (lane & 15);
        int r0 = m0 + (lane >> 4) * 4;
        float bb = b2[col];
        float a = aS[col], c = cS[col];
        float sum = 0.f, sumsq = 0.f;
#pragma unroll
        for (int j = 0; j < 4; j++) {
            float res = t1[(r0 + j) * DD + col] * a + c;
            float v0 = acc[j] + bb + res;
            t2[(r0 + j) * DD + col] = v0;
            sum += v0; sumsq += v0 * v0;
        }
        sum += __shfl_xor(sum, 16);  sum += __shfl_xor(sum, 32);
        sumsq += __shfl_xor(sumsq, 16); sumsq += __shfl_xor(sumsq, 32);
        if (lane < 16) { ps2[strip * 128 + col] = sum; pss2[strip * 128 + col] = sumsq; }
    }
}

__device__ void poolpart_phase(const float* __restrict__ t, const float* __restrict__ ps,
                               const float* __restrict__ pss, const float* __restrict__ gamma,
                               const float* __restrict__ beta, const int* __restrict__ gid,
                               float* __restrict__ poolp, int bid, int tidx) {
    if (tidx >= 128) return;
    int g = bid >> 3;
    int ch = bid & 7;
    int d = tidx;
    float s = 0.f, s2 = 0.f;
#pragma unroll 8
    for (int i = 0; i < 128; i++) { s += ps[i * 128 + d]; s2 += pss[i * 128 + d]; }
    float mean = s * (1.0f / NN);
    float var = s2 * (1.0f / NN) - mean * mean;
    float rstd = rsqrtf(var + BNEPS);
    float a = gamma[d] * rstd;
    float c = beta[d] - mean * a;
    int lo = 0, hi = NN;
    while (lo < hi) { int mid = (lo + hi) >> 1; if (gid[mid] < g) lo = mid + 1; else hi = mid; }
    int start = lo;
    lo = start; hi = NN;
    while (lo < hi) { int mid = (lo + hi) >> 1; if (gid[mid] <= g) lo = mid + 1; else hi = mid; }
    int end = lo;
    float acc = 0.f;
    for (int r = start + ch; r < end; r += 8) acc += t[r * DD + d] * a + c;
    poolp[(g * 8 + ch) * DD + d] = acc;
}

__device__ void head_phase(const float* __restrict__ poolp, const float* __restrict__ W1,
                           const float* __restrict__ b1, const float* __restrict__ W2,
                           const float* __restrict__ b2, float* __restrict__ out, int g, int tidx) {
    __shared__ float p[128], midv[128];
    if (tidx < 128) {
        float s = 0.f;
#pragma unroll
        for (int c = 0; c < 8; c++) s += poolp[(g * 8 + c) * DD + tidx];
        p[tidx] = s;
    }
    __syncthreads();
    if (tidx < 128) {
        int d = tidx;
        float acc = b1[d];
        for (int k2 = 0; k2 < 128; k2++) acc += p[k2] * W1[k2 * 128 + d];
        midv[d] = fmaxf(acc, 0.f);
    }
    __syncthreads();
    if (tidx < 64) {
        int j = tidx;
        float acc = b2[j];
        for (int k2 = 0; k2 < 128; k2++) acc += midv[k2] * W2[k2 * 64 + j];
        out[g * 64 + j] = acc;
    }
}

// ================= cooperative mega-kernel =================
struct LayerParams {
    const u32 *rowptr, *colidx, *cntv;
    const bf16x8* Wf;
    const float *bq, *bk, *bv, *bo, *g1, *be1, *b1, *b2, *g2, *be2;
    const float *mW1, *mb1, *mW2, *mb2;
    const int* gid;
    float *tA, *tB, *qb, *kb, *vb;
    unsigned short* obb;
    float *psA, *pssA, *psB, *pssB, *psv, *poolp;
    float* out;
};

__global__ __launch_bounds__(256, 4) void layers_k(LayerParams P) {
    cg::grid_group grid = cg::this_grid();
    int bid = blockIdx.x, tidx = threadIdx.x;
    // NOTE: unroll(disable) is essential — full unrolling of 8 layers inlines
    // 8 copies of every phase body and blows up compile time (R8 timeout).
#pragma clang loop unroll(disable)
    for (int l = 0; l < LL; l++) {
        const bf16x8* Wfl = P.Wf + l * 16384;
        const float* psIn  = (l == 0) ? nullptr : P.psA;
        const float* pssIn = (l == 0) ? nullptr : P.pssA;
        const float* gIn   = (l == 0) ? nullptr : (P.g2 + (l - 1) * DD);
        const float* bIn   = (l == 0) ? nullptr : (P.be2 + (l - 1) * DD);
        if (bid < 128)
            qkv_phase(P.tA, psIn, pssIn, gIn, bIn, Wfl, P.bq + l * DD, P.bk + l * DD, P.bv + l * DD,
                      P.qb, P.kb, P.vb, P.psv, bid, tidx);
        grid.sync();
        attn_phase(P.qb, P.kb, P.vb, P.rowptr, P.colidx, P.cntv, P.psv, P.obb, bid, tidx);
        grid.sync();
        if (bid < 128)
            gemmO_phase(P.obb, Wfl + 6144, P.bo + l * DD, P.tA, psIn, pssIn, gIn, bIn,
                        P.tB, P.psB, P.pssB, bid, tidx);
        grid.sync();
        if (bid < 128)
            mlp_phase(P.tB, P.psB, P.pssB, P.g1 + l * DD, P.be1 + l * DD,
                      Wfl + 8192, P.b1 + l * 2 * DD, Wfl + 12288, P.b2 + l * DD,
                      P.tA, P.psA, P.pssA, bid, tidx);
        grid.sync();
    }
    if (bid < 128)
        poolpart_phase(P.tA, P.psA, P.pssA, P.g2 + 7 * DD, P.be2 + 7 * DD, P.gid, P.poolp, bid, tidx);
    grid.sync();
    if (bid < 16)
        head_phase(P.poolp, P.mW1, P.mb1, P.mW2, P.mb2, P.out, bid, tidx);
}

// ================= fallback wrapper kernels (non-cooperative path) =================
__global__ __launch_bounds__(256) void qkv_k(const float* t, const float* ps, const float* pss,
                                             const float* gamma, const float* beta, const bf16x8* Wfl,
                                             const float* bq, const float* bk, const float* bv,
                                             float* q, float* k, float* v, float* psv) {
    qkv_phase(t, ps, pss, gamma, beta, Wfl, bq, bk, bv, q, k, v, psv, blockIdx.x, threadIdx.x);
}
__global__ __launch_bounds__(256) void attn2_k(const float* q, const float* kb, const float* vb,
                                               const u32* rowptr, const u32* colidx, const u32* cntv,
                                               const float* psv, unsigned short* obb) {
    attn_phase(q, kb, vb, rowptr, colidx, cntv, psv, obb, blockIdx.x, threadIdx.x);
}
__global__ __launch_bounds__(256) void gemmO_k(const unsigned short* obb, const bf16x8* Wfo, const float* bo,
                                               const float* tprev, const float* ps, const float* pss,
                                               const float* gamma, const float* beta,
                                               float* t1, float* ps1, float* pss1) {
    gemmO_phase(obb, Wfo, bo, tprev, ps, pss, gamma, beta, t1, ps1, pss1, blockIdx.x, threadIdx.x);
}
__global__ __launch_bounds__(256) void mlp_k(const float* t1, const float* ps1, const float* pss1,
                                             const float* g1, const float* be1,
                                             const bf16x8* Wf1, const float* b1,
                                             const bf16x8* Wf2, const float* b2,
                                             float* t2, float* ps2, float* pss2) {
    mlp_phase(t1, ps1, pss1, g1, be1, Wf1, b1, Wf2, b2, t2, ps2, pss2, blockIdx.x, threadIdx.x);
}
__global__ __launch_bounds__(256) void poolpart_k(const float* t, const float* ps, const float* pss,
                                                  const float* gamma, const float* beta, const int* gid,
                                                  float* poolp) {
    poolpart_phase(t, ps, pss, gamma, beta, gid, poolp, blockIdx.x, threadIdx.x);
}
__global__ __launch_bounds__(256) void head_k(const float* poolp, const float* W1, const float* b1,
                                              const float* W2, const float* b2, float* out) {
    head_phase(poolp, W1, b1, W2, b2, out, blockIdx.x, threadIdx.x);
}

// ---------------- host ----------------
extern "C" void kernel_launch(void* const* d_in, const int* in_sizes, int n_in,
                              void* d_out, int out_size, void* d_ws, size_t ws_size,
                              hipStream_t stream) {
    (void)n_in; (void)out_size; (void)ws_size;
    const float* X      = (const float*)d_in[0];
    const float* pos    = (const float*)d_in[1];
    const int*   ei     = (const int*)d_in[2];
    const int*   gid    = (const int*)d_in[3];
    const float* proj_W = (const float*)d_in[5];
    const float* proj_b = (const float*)d_in[6];
    const float* pe_W   = (const float*)d_in[7];
    const float* pe_b   = (const float*)d_in[8];
    const float* Wq     = (const float*)d_in[9];
    const float* bq     = (const float*)d_in[10];
    const float* Wk     = (const float*)d_in[11];
    const float* bk     = (const float*)d_in[12];
    const float* Wv     = (const float*)d_in[13];
    const float* bv     = (const float*)d_in[14];
    const float* Wo     = (const float*)d_in[15];
    const float* bo     = (const float*)d_in[16];
    const float* g1     = (const float*)d_in[17];
    const float* beta1  = (const float*)d_in[18];
    const float* W1     = (const float*)d_in[19];
    const float* b1     = (const float*)d_in[20];
    const float* W2     = (const float*)d_in[21];
    const float* b2     = (const float*)d_in[22];
    const float* g2     = (const float*)d_in[23];
    const float* beta2  = (const float*)d_in[24];
    const float* mW1    = (const float*)d_in[25];
    const float* mb1    = (const float*)d_in[26];
    const float* mW2    = (const float*)d_in[27];
    const float* mb2    = (const float*)d_in[28];
    float* out = (float*)d_out;

    int E = in_sizes[2] / 2;

    char* w = (char*)d_ws;
    u32*   Adense = (u32*)(w + 0);                         // 16 MB
    u32*   deg    = (u32*)(w + 16777216);
    u32*   rowptr = (u32*)(w + 16785408);
    u32*   colidx = (u32*)(w + 16793856);
    u32*   cntv   = (u32*)(w + 17056000);
    float* tA     = (float*)(w + 17318144);                // 1 MB
    float* tB     = (float*)(w + 18366720);                // 1 MB
    float* qb     = (float*)(w + 19415296);                // 1 MB
    float* kb     = (float*)(w + 20463872);                // 1 MB
    float* vb     = (float*)(w + 21512448);                // 1 MB
    unsigned short* obb = (unsigned short*)(w + 22561024); // 0.5 MB
    float* psA    = (float*)(w + 23085312);                // 64 KB
    float* pssA   = (float*)(w + 23150848);
    float* psB    = (float*)(w + 23216384);
    float* pssB   = (float*)(w + 23281920);
    float* psv    = (float*)(w + 23347456);
    bf16x8* Wf    = (bf16x8*)(w + 23421184);               // 2 MB
    float* poolp  = (float*)(w + 25518336);                // 64 KB

    // adjacency -> dedup'd CSR with counts (zero_k: graph-capture-safe fill)
    zero_k<<<4096, 256, 0, stream>>>((uint4*)Adense);
    scatter_k<<<(E + 255) / 256, 256, 0, stream>>>(ei, Adense, E);
    count_k<<<NN, 256, 0, stream>>>(Adense, deg);
    scan_k<<<1, 256, 0, stream>>>(deg, rowptr);
    emit_k<<<NN, 256, 0, stream>>>(Adense, rowptr, colidx, cntv);

    // weight fragments (all layers, one launch)
    wconv_k<<<512, 256, 0, stream>>>(Wq, Wk, Wv, Wo, W1, W2, (us8*)Wf);

    // input projection -> tA
    h0_k<<<NN * DD / 256, 256, 0, stream>>>(X, pos, proj_W, proj_b, pe_W, pe_b, tA);

    LayerParams hp;
    hp.rowptr = rowptr; hp.colidx = colidx; hp.cntv = cntv;
    hp.Wf = Wf;
    hp.bq = bq; hp.bk = bk; hp.bv = bv; hp.bo = bo;
    hp.g1 = g1; hp.be1 = beta1; hp.b1 = b1; hp.b2 = b2; hp.g2 = g2; hp.be2 = beta2;
    hp.mW1 = mW1; hp.mb1 = mb1; hp.mW2 = mW2; hp.mb2 = mb2;
    hp.gid = gid;
    hp.tA = tA; hp.tB = tB; hp.qb = qb; hp.kb = kb; hp.vb = vb;
    hp.obb = obb;
    hp.psA = psA; hp.pssA = pssA; hp.psB = psB; hp.pssB = pssB; hp.psv = psv; hp.poolp = poolp;
    hp.out = out;

    // Guarded cooperative launch: verify all 1024 blocks can be co-resident
    // (4 blocks/CU x 256 CUs) before attempting; any doubt -> proven fallback.
    bool coop_ok = false;
    int nb = 0;
    if (hipOccupancyMaxActiveBlocksPerMultiprocessor(&nb, (const void*)layers_k, 256, 0) == hipSuccess) {
        if (nb >= 4) coop_ok = true;
    }
    hipError_t ce = hipErrorUnknown;
    if (coop_ok) {
        void* kargs[] = { (void*)&hp };
        ce = hipLaunchCooperativeKernel((const void*)layers_k, dim3(1024), dim3(256), kargs, 0, stream);
    }
    if (ce != hipSuccess) {
        (void)hipGetLastError();   // clear error, take the multi-kernel fallback path
        for (int l = 0; l < LL; l++) {
            const bf16x8* Wfl = Wf + l * 16384;
            const float* psIn  = (l == 0) ? nullptr : psA;
            const float* pssIn = (l == 0) ? nullptr : pssA;
            const float* gIn   = (l == 0) ? nullptr : (g2 + (l - 1) * DD);
            const float* bIn   = (l == 0) ? nullptr : (beta2 + (l - 1) * DD);
            qkv_k<<<128, 256, 0, stream>>>(tA, psIn, pssIn, gIn, bIn, Wfl,
                                           bq + l * DD, bk + l * DD, bv + l * DD, qb, kb, vb, psv);
            attn2_k<<<HH * NN / 16, 256, 0, stream>>>(qb, kb, vb, rowptr, colidx, cntv, psv, obb);
            gemmO_k<<<128, 256, 0, stream>>>(obb, Wfl + 6144, bo + l * DD, tA, psIn, pssIn, gIn, bIn,
                                             tB, psB, pssB);
            mlp_k<<<128, 256, 0, stream>>>(tB, psB, pssB, g1 + l * DD, beta1 + l * DD,
                                           Wfl + 8192, b1 + l * 2 * DD, Wfl + 12288, b2 + l * DD,
                                           tA, psA, pssA);
        }
        poolpart_k<<<128, 256, 0, stream>>>(tA, psA, pssA, g2 + 7 * DD, beta2 + 7 * DD, gid, poolp);
        head_k<<<GG, 256, 0, stream>>>(poolp, mW1, mb1, mW2, mb2, out);
    }
}